// Round 1
// baseline (239.068 us; speedup 1.0000x reference)
//
#include <hip/hip_runtime.h>
#include <math.h>

// -------- physical constants (from reference) --------
#define C_ELE   332.0637f
#define C_EWF   1.12837917f
#define C_EWP   0.3275911f
#define C_A0    0.254829592f
#define C_A1   -0.284496736f
#define C_A2    1.421413741f
#define C_A3   -1.453152027f
#define C_A4    1.061405429f
#define C_BETA  18.7f
#define C_R0    2.2f
#define C_GEW   0.3f
#define C_45P6  8303.765625f   // 4.5^6
#define C_DC6I  1e-6f          // 1 / DISP_CUTOFF^6

typedef float vf4 __attribute__((ext_vector_type(4)));
typedef int   vi4 __attribute__((ext_vector_type(4)));

__device__ __forceinline__ float frcp(float x) { return __builtin_amdgcn_rcpf(x); }

struct EdgeOut { float ec, fx, fy, fz, ed, gx, gy, gz; };

// ar/ac = packed atom records: {charge, c6, r0, pad}
__device__ __forceinline__ EdgeOut edge_compute(
    vf4 ar, vf4 ac, float dx, float dy, float dz)
{
    float r2   = dx * dx + dy * dy + dz * dz;
    float rij  = sqrtf(r2);
    float rinv = frcp(rij);

    // ---- Coulomb ----
    float pref = C_ELE * ar.x * ac.x * rinv;
    float x    = (C_BETA / C_R0) * (rij - C_R0);
    float ax   = fabsf(x);
    float ex   = __expf(-ax);                 // exp(-|x|), stable
    float den  = frcp(1.0f + ex);
    float damp = (x >= 0.0f) ? den : ex * den;          // sigmoid(x)
    float sp   = (fmaxf(x, 0.0f) + __logf(1.0f + ex)) * (1.0f / C_BETA); // softplus(x)/beta
    float s    = rij * (1.0f / C_R0) * frcp(1.0f + sp);

    float grij  = C_GEW * rij;
    float expm2 = __expf(-grij * grij);
    float t     = frcp(1.0f + C_EWP * grij);
    float erfc  = t * (C_A0 + t * (C_A1 + t * (C_A2 + t * (C_A3 + t * C_A4)))) * expm2;

    EdgeOut o;
    o.ec = pref * (s + erfc - 1.0f);
    float fcl = pref * (damp * s * s + erfc + C_EWF * grij * expm2 - 1.0f);
    float fsc = fcl * frcp(r2);
    o.fx = dx * fsc; o.fy = dy * fsc; o.fz = dz * fsc;

    // ---- Dispersion (D3-CSO) ----
    float c6ij  = sqrtf(ar.y * ac.y);
    float r0ij  = 0.5f * (ar.z + ac.z);
    float r6    = r2 * r2 * r2 + C_45P6;
    float r6i   = frcp(r6);
    float e     = __expf(rij - 2.5f * r0ij);
    float onep  = frcp(1.0f + e);
    float cso   = 0.85f + 0.82f * onep;
    o.ed = -c6ij * r6i * cso + c6ij * C_DC6I;
    float r5  = r2 * r2 * rij;
    float fd  = -6.0f * c6ij * r5 * r6i * r6i * cso - c6ij * r6i * (0.82f * e * onep * onep);
    float gsc = fd * rinv;
    o.gx = dx * gsc; o.gy = dy * gsc; o.gz = dz * gsc;
    return o;
}

// Prologue: pack (charge, c6, r0) into one 16B record per atom in d_ws.
__global__ __launch_bounds__(256) void pack_atoms(
    const float* __restrict__ charge, const float* __restrict__ c6a,
    const float* __restrict__ r0a, vf4* __restrict__ tbl, int N)
{
    int i = blockIdx.x * blockDim.x + threadIdx.x;
    if (i < N) {
        vf4 v = { charge[i], c6a[i], r0a[i], 0.0f };
        tbl[i] = v;
    }
}

// ---------------------------------------------------------------------------
// Persistent grid-stride kernel, 4 edges/phase/thread, 2-deep software
// pipeline:
//   phase k:  issue idx(g_{k+2})            [consumed next phase]
//             issue dij(g_{k+1}) + gathers(g_{k+1})   [consumed next phase]
//             compute + store g_k            [hides the above latencies]
// All rotating state lives in parity ping-pong buffers (A/B, D0/D1, I0/I1)
// selected by a hand-unrolled x2 loop -> every register index is
// compile-time constant (no scratch). sched_barrier(0) pins the prefetch
// cluster above the compute so the compiler cannot sink it.
// In-order vmcnt: prefetch loads are YOUNGER than the data compute waits on,
// so they stay in flight across the wait.
// ---------------------------------------------------------------------------

#define PHASE(CUR, NXT, IR_CUR, IC_CUR, IR_NXT, IC_NXT, DCUR, DNXT)            \
  {                                                                            \
    if (g >= G) return;                                                        \
    int gn1 = g + s;                                                           \
    int gn2 = gn1 + s;                                                         \
    bool v1 = gn1 < G, v2 = gn2 < G;                                           \
    if (v2) {                                                                  \
      IR_NXT = __builtin_nontemporal_load((const vi4*)(row + 4 * (size_t)gn2));\
      IC_NXT = __builtin_nontemporal_load((const vi4*)(col + 4 * (size_t)gn2));\
    }                                                                          \
    if (v1) {                                                                  \
      const float* dp_ = dij + (size_t)gn1 * 12;                               \
      DNXT[0] = __builtin_nontemporal_load((const vf4*)(dp_ + 0));             \
      DNXT[1] = __builtin_nontemporal_load((const vf4*)(dp_ + 4));             \
      DNXT[2] = __builtin_nontemporal_load((const vf4*)(dp_ + 8));             \
      NXT[0] = tbl[IR_CUR.x]; NXT[1] = tbl[IC_CUR.x];                          \
      NXT[2] = tbl[IR_CUR.y]; NXT[3] = tbl[IC_CUR.y];                          \
      NXT[4] = tbl[IR_CUR.z]; NXT[5] = tbl[IC_CUR.z];                          \
      NXT[6] = tbl[IR_CUR.w]; NXT[7] = tbl[IC_CUR.w];                          \
    }                                                                          \
    __builtin_amdgcn_sched_barrier(0);                                         \
    {                                                                          \
      EdgeOut o0 = edge_compute(CUR[0], CUR[1], DCUR[0].x, DCUR[0].y, DCUR[0].z); \
      EdgeOut o1 = edge_compute(CUR[2], CUR[3], DCUR[0].w, DCUR[1].x, DCUR[1].y); \
      EdgeOut o2 = edge_compute(CUR[4], CUR[5], DCUR[1].z, DCUR[1].w, DCUR[2].x); \
      EdgeOut o3 = edge_compute(CUR[6], CUR[7], DCUR[2].y, DCUR[2].z, DCUR[2].w); \
      int base = g * 4;                                                        \
      vf4 ec4 = { o0.ec, o1.ec, o2.ec, o3.ec };                                \
      vf4 ed4 = { o0.ed, o1.ed, o2.ed, o3.ed };                                \
      __builtin_nontemporal_store(ec4, (vf4*)(ec_o + base));                   \
      __builtin_nontemporal_store(ed4, (vf4*)(ed_o + base));                   \
      vf4 f0v = { o0.fx, o0.fy, o0.fz, o1.fx };                                \
      vf4 f1v = { o1.fy, o1.fz, o2.fx, o2.fy };                                \
      vf4 f2v = { o2.fz, o3.fx, o3.fy, o3.fz };                                \
      float* cfp = cf_o + (size_t)base * 3;                                    \
      __builtin_nontemporal_store(f0v, (vf4*)(cfp + 0));                       \
      __builtin_nontemporal_store(f1v, (vf4*)(cfp + 4));                       \
      __builtin_nontemporal_store(f2v, (vf4*)(cfp + 8));                       \
      vf4 g0v = { o0.gx, o0.gy, o0.gz, o1.gx };                                \
      vf4 g1v = { o1.gy, o1.gz, o2.gx, o2.gy };                                \
      vf4 g2v = { o2.gz, o3.gx, o3.gy, o3.gz };                                \
      float* dfp = df_o + (size_t)base * 3;                                    \
      __builtin_nontemporal_store(g0v, (vf4*)(dfp + 0));                       \
      __builtin_nontemporal_store(g1v, (vf4*)(dfp + 4));                       \
      __builtin_nontemporal_store(g2v, (vf4*)(dfp + 8));                       \
    }                                                                          \
    g = gn1;                                                                   \
  }

__global__ __launch_bounds__(256, 3) void bamboo_pipe(
    const int* __restrict__ row, const int* __restrict__ col,
    const float* __restrict__ dij,
    const vf4* __restrict__ tbl,
    float* __restrict__ out, int E)
{
    const int G = E >> 2;                       // groups of 4 edges
    const int s = gridDim.x * blockDim.x;       // stride in groups
    int g = blockIdx.x * blockDim.x + threadIdx.x;
    if (g >= G) return;

    float* __restrict__ ec_o = out;
    float* __restrict__ cf_o = out + (size_t)E;
    float* __restrict__ ed_o = out + (size_t)4 * E;
    float* __restrict__ df_o = out + (size_t)5 * E;

    vf4 A[8], B[8];          // atom-record ping-pong (gather destinations)
    vf4 D0[3], D1[3];        // dij ping-pong
    vi4 rI0, cI0, rI1, cI1;  // index ping-pong

    // ---- pipeline fill ----
    {
        vi4 rr = __builtin_nontemporal_load((const vi4*)(row + 4 * (size_t)g));
        vi4 cc = __builtin_nontemporal_load((const vi4*)(col + 4 * (size_t)g));
        const float* dp = dij + (size_t)g * 12;
        D0[0] = __builtin_nontemporal_load((const vf4*)(dp + 0));
        D0[1] = __builtin_nontemporal_load((const vf4*)(dp + 4));
        D0[2] = __builtin_nontemporal_load((const vf4*)(dp + 8));
        int g1 = g + s;
        if (g1 < G) {
            rI0 = __builtin_nontemporal_load((const vi4*)(row + 4 * (size_t)g1));
            cI0 = __builtin_nontemporal_load((const vi4*)(col + 4 * (size_t)g1));
        }
        __builtin_amdgcn_sched_barrier(0);
        A[0] = tbl[rr.x]; A[1] = tbl[cc.x];
        A[2] = tbl[rr.y]; A[3] = tbl[cc.y];
        A[4] = tbl[rr.z]; A[5] = tbl[cc.z];
        A[6] = tbl[rr.w]; A[7] = tbl[cc.w];
        __builtin_amdgcn_sched_barrier(0);
    }

    // ---- steady state: parity-unrolled so all buffer indices are static ----
    for (;;) {
        PHASE(A, B, rI0, cI0, rI1, cI1, D0, D1);
        PHASE(B, A, rI1, cI1, rI0, cI0, D1, D0);
    }
}

// Scalar fallback (handles E%4!=0 / tiny workspace).
__global__ __launch_bounds__(256) void bamboo_scalar(
    const int* __restrict__ row, const int* __restrict__ col,
    const float* __restrict__ dij,
    const float* __restrict__ charge, const float* __restrict__ c6a,
    const float* __restrict__ r0a,
    float* __restrict__ out, int E, int start)
{
    int j = start + blockIdx.x * blockDim.x + threadIdx.x;
    if (j >= E) return;
    float* ec_o = out;
    float* cf_o = out + (size_t)E;
    float* ed_o = out + (size_t)4 * E;
    float* df_o = out + (size_t)5 * E;
    int r = row[j], c = col[j];
    vf4 ar = { charge[r], c6a[r], r0a[r], 0.0f };
    vf4 ac = { charge[c], c6a[c], r0a[c], 0.0f };
    EdgeOut o = edge_compute(ar, ac,
                             dij[3 * (size_t)j], dij[3 * (size_t)j + 1], dij[3 * (size_t)j + 2]);
    ec_o[j] = o.ec; ed_o[j] = o.ed;
    cf_o[3 * (size_t)j] = o.fx; cf_o[3 * (size_t)j + 1] = o.fy; cf_o[3 * (size_t)j + 2] = o.fz;
    df_o[3 * (size_t)j] = o.gx; df_o[3 * (size_t)j + 1] = o.gy; df_o[3 * (size_t)j + 2] = o.gz;
}

extern "C" void kernel_launch(void* const* d_in, const int* in_sizes, int n_in,
                              void* d_out, int out_size, void* d_ws, size_t ws_size,
                              hipStream_t stream) {
    const int*   row    = (const int*)d_in[0];
    const int*   col    = (const int*)d_in[1];
    const float* dij    = (const float*)d_in[2];
    const float* charge = (const float*)d_in[3];
    const float* c6a    = (const float*)d_in[4];
    const float* r0a    = (const float*)d_in[5];
    float* out = (float*)d_out;
    int E = in_sizes[0];
    int N = in_sizes[3];

    size_t need = (size_t)N * sizeof(vf4);
    if (ws_size >= need && ((uintptr_t)d_ws % 16) == 0 && (E & 3) == 0) {
        vf4* tbl = (vf4*)d_ws;
        pack_atoms<<<(N + 255) / 256, 256, 0, stream>>>(charge, c6a, r0a, tbl, N);
        int groups = E / 4;
        // persistent-style launch: 3 blocks/CU x 256 CUs resident, ~5 phases/thread
        int blocks = (groups + 255) / 256;
        if (blocks > 768) blocks = 768;
        bamboo_pipe<<<blocks, 256, 0, stream>>>(row, col, dij, tbl, out, E);
    } else {
        bamboo_scalar<<<(E + 255) / 256, 256, 0, stream>>>(row, col, dij, charge, c6a, r0a, out, E, 0);
    }
}

// Round 2
// 231.151 us; speedup vs baseline: 1.0343x; 1.0343x over previous
//
#include <hip/hip_runtime.h>
#include <math.h>

// -------- physical constants (from reference) --------
#define C_ELE   332.0637f
#define C_EWF   1.12837917f
#define C_EWP   0.3275911f
#define C_A0    0.254829592f
#define C_A1   -0.284496736f
#define C_A2    1.421413741f
#define C_A3   -1.453152027f
#define C_A4    1.061405429f
#define C_BETA  18.7f
#define C_R0    2.2f
#define C_GEW   0.3f
#define C_45P6  8303.765625f   // 4.5^6
#define C_DC6I  1e-6f          // 1 / DISP_CUTOFF^6

typedef float vf4 __attribute__((ext_vector_type(4)));
typedef int   vi4 __attribute__((ext_vector_type(4)));

__device__ __forceinline__ float frcp(float x) { return __builtin_amdgcn_rcpf(x); }

struct EdgeOut { float ec, fx, fy, fz, ed, gx, gy, gz; };

// ar/ac = packed atom records: {charge, c6, r0, pad}
__device__ __forceinline__ EdgeOut edge_compute(
    vf4 ar, vf4 ac, float dx, float dy, float dz)
{
    float r2   = dx * dx + dy * dy + dz * dz;
    float rij  = sqrtf(r2);
    float rinv = frcp(rij);

    // ---- Coulomb ----
    float pref = C_ELE * ar.x * ac.x * rinv;
    float x    = (C_BETA / C_R0) * (rij - C_R0);
    float ax   = fabsf(x);
    float ex   = __expf(-ax);                 // exp(-|x|), stable
    float den  = frcp(1.0f + ex);
    float damp = (x >= 0.0f) ? den : ex * den;          // sigmoid(x)
    float sp   = (fmaxf(x, 0.0f) + __logf(1.0f + ex)) * (1.0f / C_BETA); // softplus(x)/beta
    float s    = rij * (1.0f / C_R0) * frcp(1.0f + sp);

    float grij  = C_GEW * rij;
    float expm2 = __expf(-grij * grij);
    float t     = frcp(1.0f + C_EWP * grij);
    float erfc  = t * (C_A0 + t * (C_A1 + t * (C_A2 + t * (C_A3 + t * C_A4)))) * expm2;

    EdgeOut o;
    o.ec = pref * (s + erfc - 1.0f);
    float fcl = pref * (damp * s * s + erfc + C_EWF * grij * expm2 - 1.0f);
    float fsc = fcl * frcp(r2);
    o.fx = dx * fsc; o.fy = dy * fsc; o.fz = dz * fsc;

    // ---- Dispersion (D3-CSO) ----
    float c6ij  = sqrtf(ar.y * ac.y);
    float r0ij  = 0.5f * (ar.z + ac.z);
    float r6    = r2 * r2 * r2 + C_45P6;
    float r6i   = frcp(r6);
    float e     = __expf(rij - 2.5f * r0ij);
    float onep  = frcp(1.0f + e);
    float cso   = 0.85f + 0.82f * onep;
    o.ed = -c6ij * r6i * cso + c6ij * C_DC6I;
    float r5  = r2 * r2 * rij;
    float fd  = -6.0f * c6ij * r5 * r6i * r6i * cso - c6ij * r6i * (0.82f * e * onep * onep);
    float gsc = fd * rinv;
    o.gx = dx * gsc; o.gy = dy * gsc; o.gz = dz * gsc;
    return o;
}

// Prologue: pack (charge, c6, r0) into one 16B record per atom in d_ws.
__global__ __launch_bounds__(256) void pack_atoms(
    const float* __restrict__ charge, const float* __restrict__ c6a,
    const float* __restrict__ r0a, vf4* __restrict__ tbl, int N)
{
    int i = blockIdx.x * blockDim.x + threadIdx.x;
    if (i < N) {
        vf4 v = { charge[i], c6a[i], r0a[i], 0.0f };
        tbl[i] = v;
    }
}

// ---------------------------------------------------------------------------
// Transaction-minimized kernel. One block = 1024 edges (4 per thread).
// All strided global accesses (dij loads at 48B lane-stride, cf/df stores at
// 48B lane-stride) are converted to fully-coalesced vf4 accesses through LDS
// transpose staging. The only remaining divergent traffic is the 8 atom-table
// gathers per thread, which are irreducible (random indices).
//
// LDS layout: per-thread slot of 13 dwords (12 payload + 1 pad).
//   - reads  at lane-stride 13 dwords -> gcd(13,32)=1 -> bank-conflict-free
//   - staging writes/reads at flat position v=vf4 index: q=v/3, r=v%3,
//     dword base q*13+4r -> contiguous 4-dword span, ~2-way conflicts (free).
// tx/wave-phase: 1008 -> 720 (-29%).
// ---------------------------------------------------------------------------
__global__ __launch_bounds__(256) void bamboo_lds(
    const int* __restrict__ row, const int* __restrict__ col,
    const float* __restrict__ dij,
    const vf4* __restrict__ tbl,
    float* __restrict__ out, int E)
{
    __shared__ float s_dij[256 * 13];
    __shared__ float s_cf [256 * 13];
    __shared__ float s_df [256 * 13];

    const int t     = threadIdx.x;
    const int ebase = blockIdx.x << 10;          // first edge of this tile
    const int gbase = ebase + t * 4;             // this thread's first edge

    float* __restrict__ ec_o = out;
    float* __restrict__ cf_o = out + (size_t)E;
    float* __restrict__ ed_o = out + (size_t)4 * E;
    float* __restrict__ df_o = out + (size_t)5 * E;

    // ---- head of dependency chain: indices (gathers depend on these) ----
    vi4 rr = __builtin_nontemporal_load((const vi4*)(row + gbase));
    vi4 cc = __builtin_nontemporal_load((const vi4*)(col + gbase));

    // ---- coalesced dij stream: 3 vf4/thread, lane-contiguous ----
    const vf4* dstream = (const vf4*)(dij + (size_t)ebase * 3);
    vf4 d0 = __builtin_nontemporal_load(dstream + (0 * 256 + t));
    vf4 d1 = __builtin_nontemporal_load(dstream + (1 * 256 + t));
    vf4 d2 = __builtin_nontemporal_load(dstream + (2 * 256 + t));
    __builtin_amdgcn_sched_barrier(0);

    // ---- all 8 gathers in flight before anything waits ----
    vf4 a0r = tbl[rr.x]; vf4 a0c = tbl[cc.x];
    vf4 a1r = tbl[rr.y]; vf4 a1c = tbl[cc.y];
    vf4 a2r = tbl[rr.z]; vf4 a2c = tbl[cc.z];
    vf4 a3r = tbl[rr.w]; vf4 a3c = tbl[cc.w];
    __builtin_amdgcn_sched_barrier(0);

    // ---- scatter the coalesced dij vf4s into padded per-thread slots ----
    // vf4 index v holds flat floats 4v..4v+3 = edge-group q=v/3, dword 4r+k.
    {
        int v, q, r, b;
        v = 0 * 256 + t; q = v / 3; r = v - 3 * q; b = q * 13 + 4 * r;
        s_dij[b + 0] = d0.x; s_dij[b + 1] = d0.y; s_dij[b + 2] = d0.z; s_dij[b + 3] = d0.w;
        v = 1 * 256 + t; q = v / 3; r = v - 3 * q; b = q * 13 + 4 * r;
        s_dij[b + 0] = d1.x; s_dij[b + 1] = d1.y; s_dij[b + 2] = d1.z; s_dij[b + 3] = d1.w;
        v = 2 * 256 + t; q = v / 3; r = v - 3 * q; b = q * 13 + 4 * r;
        s_dij[b + 0] = d2.x; s_dij[b + 1] = d2.y; s_dij[b + 2] = d2.z; s_dij[b + 3] = d2.w;
    }
    __syncthreads();

    // ---- own dij: conflict-free stride-13 reads ----
    float d[12];
    #pragma unroll
    for (int m = 0; m < 12; ++m) d[m] = s_dij[t * 13 + m];

    EdgeOut o0 = edge_compute(a0r, a0c, d[0],  d[1],  d[2]);
    EdgeOut o1 = edge_compute(a1r, a1c, d[3],  d[4],  d[5]);
    EdgeOut o2 = edge_compute(a2r, a2c, d[6],  d[7],  d[8]);
    EdgeOut o3 = edge_compute(a3r, a3c, d[9],  d[10], d[11]);

    // ---- ec/ed: already coalesced, store direct ----
    vf4 ec4 = { o0.ec, o1.ec, o2.ec, o3.ec };
    vf4 ed4 = { o0.ed, o1.ed, o2.ed, o3.ed };
    __builtin_nontemporal_store(ec4, (vf4*)(ec_o + gbase));
    __builtin_nontemporal_store(ed4, (vf4*)(ed_o + gbase));

    // ---- forces into LDS (stride-13, conflict-free) ----
    {
        float* cf = s_cf + t * 13;
        float* df = s_df + t * 13;
        cf[0]  = o0.fx; cf[1]  = o0.fy; cf[2]  = o0.fz;
        cf[3]  = o1.fx; cf[4]  = o1.fy; cf[5]  = o1.fz;
        cf[6]  = o2.fx; cf[7]  = o2.fy; cf[8]  = o2.fz;
        cf[9]  = o3.fx; cf[10] = o3.fy; cf[11] = o3.fz;
        df[0]  = o0.gx; df[1]  = o0.gy; df[2]  = o0.gz;
        df[3]  = o1.gx; df[4]  = o1.gy; df[5]  = o1.gz;
        df[6]  = o2.gx; df[7]  = o2.gy; df[8]  = o2.gz;
        df[9]  = o3.gx; df[10] = o3.gy; df[11] = o3.gz;
    }
    __syncthreads();

    // ---- coalesced force store-out: 3 vf4/thread each ----
    vf4* cf_out = (vf4*)(cf_o + (size_t)ebase * 3);
    vf4* df_out = (vf4*)(df_o + (size_t)ebase * 3);
    #pragma unroll
    for (int j = 0; j < 3; ++j) {
        int v = j * 256 + t;
        int q = v / 3, r = v - 3 * q, b = q * 13 + 4 * r;
        vf4 wc = { s_cf[b], s_cf[b + 1], s_cf[b + 2], s_cf[b + 3] };
        __builtin_nontemporal_store(wc, cf_out + v);
        vf4 wd = { s_df[b], s_df[b + 1], s_df[b + 2], s_df[b + 3] };
        __builtin_nontemporal_store(wd, df_out + v);
    }
}

// Scalar fallback (tail edges / tiny workspace).
__global__ __launch_bounds__(256) void bamboo_scalar(
    const int* __restrict__ row, const int* __restrict__ col,
    const float* __restrict__ dij,
    const float* __restrict__ charge, const float* __restrict__ c6a,
    const float* __restrict__ r0a,
    float* __restrict__ out, int E, int start)
{
    int j = start + blockIdx.x * blockDim.x + threadIdx.x;
    if (j >= E) return;
    float* ec_o = out;
    float* cf_o = out + (size_t)E;
    float* ed_o = out + (size_t)4 * E;
    float* df_o = out + (size_t)5 * E;
    int r = row[j], c = col[j];
    vf4 ar = { charge[r], c6a[r], r0a[r], 0.0f };
    vf4 ac = { charge[c], c6a[c], r0a[c], 0.0f };
    EdgeOut o = edge_compute(ar, ac,
                             dij[3 * (size_t)j], dij[3 * (size_t)j + 1], dij[3 * (size_t)j + 2]);
    ec_o[j] = o.ec; ed_o[j] = o.ed;
    cf_o[3 * (size_t)j] = o.fx; cf_o[3 * (size_t)j + 1] = o.fy; cf_o[3 * (size_t)j + 2] = o.fz;
    df_o[3 * (size_t)j] = o.gx; df_o[3 * (size_t)j + 1] = o.gy; df_o[3 * (size_t)j + 2] = o.gz;
}

extern "C" void kernel_launch(void* const* d_in, const int* in_sizes, int n_in,
                              void* d_out, int out_size, void* d_ws, size_t ws_size,
                              hipStream_t stream) {
    const int*   row    = (const int*)d_in[0];
    const int*   col    = (const int*)d_in[1];
    const float* dij    = (const float*)d_in[2];
    const float* charge = (const float*)d_in[3];
    const float* c6a    = (const float*)d_in[4];
    const float* r0a    = (const float*)d_in[5];
    float* out = (float*)d_out;
    int E = in_sizes[0];
    int N = in_sizes[3];

    size_t need = (size_t)N * sizeof(vf4);
    if (ws_size >= need && ((uintptr_t)d_ws % 16) == 0) {
        vf4* tbl = (vf4*)d_ws;
        pack_atoms<<<(N + 255) / 256, 256, 0, stream>>>(charge, c6a, r0a, tbl, N);
        int ntiles = E >> 10;                    // 1024 edges per tile
        int tail   = ntiles << 10;
        if (ntiles > 0)
            bamboo_lds<<<ntiles, 256, 0, stream>>>(row, col, dij, tbl, out, E);
        if (tail < E)
            bamboo_scalar<<<(E - tail + 255) / 256, 256, 0, stream>>>(
                row, col, dij, charge, c6a, r0a, out, E, tail);
    } else {
        bamboo_scalar<<<(E + 255) / 256, 256, 0, stream>>>(row, col, dij, charge, c6a, r0a, out, E, 0);
    }
}

// Round 3
// 229.646 us; speedup vs baseline: 1.0410x; 1.0066x over previous
//
#include <hip/hip_runtime.h>
#include <math.h>

// -------- physical constants (from reference) --------
#define C_ELE   332.0637f
#define C_EWF   1.12837917f
#define C_EWP   0.3275911f
#define C_A0    0.254829592f
#define C_A1   -0.284496736f
#define C_A2    1.421413741f
#define C_A3   -1.453152027f
#define C_A4    1.061405429f
#define C_BETA  18.7f
#define C_R0    2.2f
#define C_GEW   0.3f
#define C_45P6  8303.765625f   // 4.5^6
#define C_DC6I  1e-6f          // 1 / DISP_CUTOFF^6

typedef float  vf4 __attribute__((ext_vector_type(4)));
typedef int    vi4 __attribute__((ext_vector_type(4)));
typedef int    vi2 __attribute__((ext_vector_type(2)));
typedef __fp16 vh2 __attribute__((ext_vector_type(2)));

__device__ __forceinline__ float frcp(float x) { return __builtin_amdgcn_rcpf(x); }

struct EdgeOut { float ec, fx, fy, fz, ed, gx, gy, gz; };

// 8-byte atom record: {f32 charge, f16 c6, f16 r0}
__device__ __forceinline__ vf4 unpack8(vi2 v)
{
    union { int i; vh2 h; } u; u.i = v.y;
    vf4 r = { __int_as_float(v.x), (float)u.h.x, (float)u.h.y, 0.0f };
    return r;
}

// ar/ac = {charge, c6, r0, pad}
__device__ __forceinline__ EdgeOut edge_compute(
    vf4 ar, vf4 ac, float dx, float dy, float dz)
{
    float r2   = dx * dx + dy * dy + dz * dz;
    float rij  = sqrtf(r2);
    float rinv = frcp(rij);

    // ---- Coulomb ----
    float pref = C_ELE * ar.x * ac.x * rinv;
    float x    = (C_BETA / C_R0) * (rij - C_R0);
    float ax   = fabsf(x);
    float ex   = __expf(-ax);                 // exp(-|x|), stable
    float den  = frcp(1.0f + ex);
    float damp = (x >= 0.0f) ? den : ex * den;          // sigmoid(x)
    float sp   = (fmaxf(x, 0.0f) + __logf(1.0f + ex)) * (1.0f / C_BETA); // softplus(x)/beta
    float s    = rij * (1.0f / C_R0) * frcp(1.0f + sp);

    float grij  = C_GEW * rij;
    float expm2 = __expf(-grij * grij);
    float t     = frcp(1.0f + C_EWP * grij);
    float erfc  = t * (C_A0 + t * (C_A1 + t * (C_A2 + t * (C_A3 + t * C_A4)))) * expm2;

    EdgeOut o;
    o.ec = pref * (s + erfc - 1.0f);
    float fcl = pref * (damp * s * s + erfc + C_EWF * grij * expm2 - 1.0f);
    float fsc = fcl * frcp(r2);
    o.fx = dx * fsc; o.fy = dy * fsc; o.fz = dz * fsc;

    // ---- Dispersion (D3-CSO) ----
    float c6ij  = sqrtf(ar.y * ac.y);
    float r0ij  = 0.5f * (ar.z + ac.z);
    float r6    = r2 * r2 * r2 + C_45P6;
    float r6i   = frcp(r6);
    float e     = __expf(rij - 2.5f * r0ij);
    float onep  = frcp(1.0f + e);
    float cso   = 0.85f + 0.82f * onep;
    o.ed = -c6ij * r6i * cso + c6ij * C_DC6I;
    float r5  = r2 * r2 * rij;
    float fd  = -6.0f * c6ij * r5 * r6i * r6i * cso - c6ij * r6i * (0.82f * e * onep * onep);
    float gsc = fd * rinv;
    o.gx = dx * gsc; o.gy = dy * gsc; o.gz = dz * gsc;
    return o;
}

// Prologue: pack (f32 charge | f16 c6 | f16 r0) into one 8B record per atom.
// pkrtz: round-to-zero f32->f16, rel err <= 2^-11; only perturbs dispersion
// terms whose magnitude is ~1e-2, so added output error ~1e-5.
__global__ __launch_bounds__(256) void pack_atoms8(
    const float* __restrict__ charge, const float* __restrict__ c6a,
    const float* __restrict__ r0a, vi2* __restrict__ tbl, int N)
{
    int i = blockIdx.x * blockDim.x + threadIdx.x;
    if (i < N) {
        vh2 h = __builtin_amdgcn_cvt_pkrtz(c6a[i], r0a[i]);
        union { vh2 h; int i; } u; u.h = h;
        vi2 v = { __float_as_int(charge[i]), u.i };
        tbl[i] = v;
    }
}

// ---------------------------------------------------------------------------
// One block = 1024 edges (4/thread). Strided global accesses (dij loads,
// cf/df stores, 48B lane-stride) go through LDS transpose staging so every
// global access is a coalesced vf4. Gathers are 8B records from a 1.6MB
// table (L2-resident even alongside the streaming traffic).
// LDS: two 13.3KB buffers (s_a: dij then df; s_b: cf) -> 26.6KB/block,
// 6 blocks/CU. Per-thread slot = 13 dwords (12 payload + 1 pad): stride-13
// lane access is bank-conflict-free (gcd(13,32)=1).
// Tail edges (E % 1024) are handled by block 0, no extra dispatch.
// ---------------------------------------------------------------------------
__global__ __launch_bounds__(256, 4) void bamboo_lds8(
    const int* __restrict__ row, const int* __restrict__ col,
    const float* __restrict__ dij,
    const vi2* __restrict__ tbl,
    float* __restrict__ out, int E)
{
    __shared__ float s_a[256 * 13];   // dij in, then df
    __shared__ float s_b[256 * 13];   // cf

    const int t     = threadIdx.x;
    const int ebase = blockIdx.x << 10;
    const int gbase = ebase + t * 4;

    float* __restrict__ ec_o = out;
    float* __restrict__ cf_o = out + (size_t)E;
    float* __restrict__ ed_o = out + (size_t)4 * E;
    float* __restrict__ df_o = out + (size_t)5 * E;

    // ---- head of chain: indices (gathers depend on these) ----
    vi4 rr = __builtin_nontemporal_load((const vi4*)(row + gbase));
    vi4 cc = __builtin_nontemporal_load((const vi4*)(col + gbase));

    // ---- coalesced dij stream: 3 vf4/thread ----
    const vf4* dstream = (const vf4*)(dij + (size_t)ebase * 3);
    vf4 d0 = __builtin_nontemporal_load(dstream + (0 * 256 + t));
    vf4 d1 = __builtin_nontemporal_load(dstream + (1 * 256 + t));
    vf4 d2 = __builtin_nontemporal_load(dstream + (2 * 256 + t));
    __builtin_amdgcn_sched_barrier(0);

    // ---- all 8 gathers in flight back-to-back (8B each) ----
    vi2 g0r = tbl[rr.x]; vi2 g0c = tbl[cc.x];
    vi2 g1r = tbl[rr.y]; vi2 g1c = tbl[cc.y];
    vi2 g2r = tbl[rr.z]; vi2 g2c = tbl[cc.z];
    vi2 g3r = tbl[rr.w]; vi2 g3c = tbl[cc.w];
    __builtin_amdgcn_sched_barrier(0);

    // ---- scatter coalesced dij vf4s into padded per-thread slots ----
    // vf4 index v holds flat floats 4v..4v+3 = slot q=v/3, dword 4r.
    {
        int v, q, r, b;
        v = 0 * 256 + t; q = v / 3; r = v - 3 * q; b = q * 13 + 4 * r;
        s_a[b + 0] = d0.x; s_a[b + 1] = d0.y; s_a[b + 2] = d0.z; s_a[b + 3] = d0.w;
        v = 1 * 256 + t; q = v / 3; r = v - 3 * q; b = q * 13 + 4 * r;
        s_a[b + 0] = d1.x; s_a[b + 1] = d1.y; s_a[b + 2] = d1.z; s_a[b + 3] = d1.w;
        v = 2 * 256 + t; q = v / 3; r = v - 3 * q; b = q * 13 + 4 * r;
        s_a[b + 0] = d2.x; s_a[b + 1] = d2.y; s_a[b + 2] = d2.z; s_a[b + 3] = d2.w;
    }
    __syncthreads();

    // ---- own dij: conflict-free stride-13 reads ----
    float d[12];
    #pragma unroll
    for (int m = 0; m < 12; ++m) d[m] = s_a[t * 13 + m];
    __syncthreads();                  // s_a free for reuse (df)

    EdgeOut o0 = edge_compute(unpack8(g0r), unpack8(g0c), d[0], d[1],  d[2]);
    EdgeOut o1 = edge_compute(unpack8(g1r), unpack8(g1c), d[3], d[4],  d[5]);
    EdgeOut o2 = edge_compute(unpack8(g2r), unpack8(g2c), d[6], d[7],  d[8]);
    EdgeOut o3 = edge_compute(unpack8(g3r), unpack8(g3c), d[9], d[10], d[11]);

    // ---- ec/ed: already coalesced, store direct ----
    vf4 ec4 = { o0.ec, o1.ec, o2.ec, o3.ec };
    vf4 ed4 = { o0.ed, o1.ed, o2.ed, o3.ed };
    __builtin_nontemporal_store(ec4, (vf4*)(ec_o + gbase));
    __builtin_nontemporal_store(ed4, (vf4*)(ed_o + gbase));

    // ---- forces into LDS (stride-13, conflict-free) ----
    {
        float* cf = s_b + t * 13;
        float* df = s_a + t * 13;
        cf[0]  = o0.fx; cf[1]  = o0.fy; cf[2]  = o0.fz;
        cf[3]  = o1.fx; cf[4]  = o1.fy; cf[5]  = o1.fz;
        cf[6]  = o2.fx; cf[7]  = o2.fy; cf[8]  = o2.fz;
        cf[9]  = o3.fx; cf[10] = o3.fy; cf[11] = o3.fz;
        df[0]  = o0.gx; df[1]  = o0.gy; df[2]  = o0.gz;
        df[3]  = o1.gx; df[4]  = o1.gy; df[5]  = o1.gz;
        df[6]  = o2.gx; df[7]  = o2.gy; df[8]  = o2.gz;
        df[9]  = o3.gx; df[10] = o3.gy; df[11] = o3.gz;
    }
    __syncthreads();

    // ---- coalesced force store-out: 3 vf4/thread each ----
    vf4* cf_out = (vf4*)(cf_o + (size_t)ebase * 3);
    vf4* df_out = (vf4*)(df_o + (size_t)ebase * 3);
    #pragma unroll
    for (int j = 0; j < 3; ++j) {
        int v = j * 256 + t;
        int q = v / 3, r = v - 3 * q, b = q * 13 + 4 * r;
        vf4 wc = { s_b[b], s_b[b + 1], s_b[b + 2], s_b[b + 3] };
        __builtin_nontemporal_store(wc, cf_out + v);
        vf4 wd = { s_a[b], s_a[b + 1], s_a[b + 2], s_a[b + 3] };
        __builtin_nontemporal_store(wd, df_out + v);
    }

    // ---- tail edges (E % 1024), handled by block 0: no extra dispatch ----
    if (blockIdx.x == 0) {
        for (int j = ((int)gridDim.x << 10) + t; j < E; j += 256) {
            vi2 vr = tbl[row[j]];
            vi2 vc = tbl[col[j]];
            EdgeOut o = edge_compute(unpack8(vr), unpack8(vc),
                                     dij[3 * (size_t)j], dij[3 * (size_t)j + 1],
                                     dij[3 * (size_t)j + 2]);
            ec_o[j] = o.ec; ed_o[j] = o.ed;
            cf_o[3 * (size_t)j] = o.fx; cf_o[3 * (size_t)j + 1] = o.fy; cf_o[3 * (size_t)j + 2] = o.fz;
            df_o[3 * (size_t)j] = o.gx; df_o[3 * (size_t)j + 1] = o.gy; df_o[3 * (size_t)j + 2] = o.gz;
        }
    }
}

// Full scalar fallback (tiny workspace only).
__global__ __launch_bounds__(256) void bamboo_scalar(
    const int* __restrict__ row, const int* __restrict__ col,
    const float* __restrict__ dij,
    const float* __restrict__ charge, const float* __restrict__ c6a,
    const float* __restrict__ r0a,
    float* __restrict__ out, int E, int start)
{
    int j = start + blockIdx.x * blockDim.x + threadIdx.x;
    if (j >= E) return;
    float* ec_o = out;
    float* cf_o = out + (size_t)E;
    float* ed_o = out + (size_t)4 * E;
    float* df_o = out + (size_t)5 * E;
    int r = row[j], c = col[j];
    vf4 ar = { charge[r], c6a[r], r0a[r], 0.0f };
    vf4 ac = { charge[c], c6a[c], r0a[c], 0.0f };
    EdgeOut o = edge_compute(ar, ac,
                             dij[3 * (size_t)j], dij[3 * (size_t)j + 1], dij[3 * (size_t)j + 2]);
    ec_o[j] = o.ec; ed_o[j] = o.ed;
    cf_o[3 * (size_t)j] = o.fx; cf_o[3 * (size_t)j + 1] = o.fy; cf_o[3 * (size_t)j + 2] = o.fz;
    df_o[3 * (size_t)j] = o.gx; df_o[3 * (size_t)j + 1] = o.gy; df_o[3 * (size_t)j + 2] = o.gz;
}

extern "C" void kernel_launch(void* const* d_in, const int* in_sizes, int n_in,
                              void* d_out, int out_size, void* d_ws, size_t ws_size,
                              hipStream_t stream) {
    const int*   row    = (const int*)d_in[0];
    const int*   col    = (const int*)d_in[1];
    const float* dij    = (const float*)d_in[2];
    const float* charge = (const float*)d_in[3];
    const float* c6a    = (const float*)d_in[4];
    const float* r0a    = (const float*)d_in[5];
    float* out = (float*)d_out;
    int E = in_sizes[0];
    int N = in_sizes[3];

    size_t need = (size_t)N * sizeof(vi2);
    int ntiles = E >> 10;
    if (ws_size >= need && ((uintptr_t)d_ws % 8) == 0 && ntiles > 0) {
        vi2* tbl = (vi2*)d_ws;
        pack_atoms8<<<(N + 255) / 256, 256, 0, stream>>>(charge, c6a, r0a, tbl, N);
        bamboo_lds8<<<ntiles, 256, 0, stream>>>(row, col, dij, tbl, out, E);
    } else {
        bamboo_scalar<<<(E + 255) / 256, 256, 0, stream>>>(row, col, dij, charge, c6a, r0a, out, E, 0);
    }
}

// Round 4
// 227.581 us; speedup vs baseline: 1.0505x; 1.0091x over previous
//
#include <hip/hip_runtime.h>
#include <math.h>

// -------- physical constants (from reference) --------
#define C_ELE   332.0637f
#define C_EWF   1.12837917f
#define C_EWP   0.3275911f
#define C_A0    0.254829592f
#define C_A1   -0.284496736f
#define C_A2    1.421413741f
#define C_A3   -1.453152027f
#define C_A4    1.061405429f
#define C_BETA  18.7f
#define C_R0    2.2f
#define C_GEW   0.3f
#define C_45P6  8303.765625f   // 4.5^6
#define C_DC6I  1e-6f          // 1 / DISP_CUTOFF^6

typedef float  vf4 __attribute__((ext_vector_type(4)));
typedef int    vi4 __attribute__((ext_vector_type(4)));
typedef int    vi2 __attribute__((ext_vector_type(2)));
typedef __fp16 vh2 __attribute__((ext_vector_type(2)));

__device__ __forceinline__ float frcp(float x) { return __builtin_amdgcn_rcpf(x); }

struct EdgeOut { float ec, fx, fy, fz, ed, gx, gy, gz; };

// 8-byte atom record: {f32 charge, f16 c6, f16 r0}
__device__ __forceinline__ vf4 unpack8(vi2 v)
{
    union { int i; vh2 h; } u; u.i = v.y;
    vf4 r = { __int_as_float(v.x), (float)u.h.x, (float)u.h.y, 0.0f };
    return r;
}

// ar/ac = {charge, c6, r0, pad}
__device__ __forceinline__ EdgeOut edge_compute(
    vf4 ar, vf4 ac, float dx, float dy, float dz)
{
    float r2   = dx * dx + dy * dy + dz * dz;
    float rij  = sqrtf(r2);
    float rinv = frcp(rij);

    // ---- Coulomb ----
    float pref = C_ELE * ar.x * ac.x * rinv;
    float x    = (C_BETA / C_R0) * (rij - C_R0);
    float ax   = fabsf(x);
    float ex   = __expf(-ax);                 // exp(-|x|), stable
    float den  = frcp(1.0f + ex);
    float damp = (x >= 0.0f) ? den : ex * den;          // sigmoid(x)
    float sp   = (fmaxf(x, 0.0f) + __logf(1.0f + ex)) * (1.0f / C_BETA); // softplus(x)/beta
    float s    = rij * (1.0f / C_R0) * frcp(1.0f + sp);

    float grij  = C_GEW * rij;
    float expm2 = __expf(-grij * grij);
    float t     = frcp(1.0f + C_EWP * grij);
    float erfc  = t * (C_A0 + t * (C_A1 + t * (C_A2 + t * (C_A3 + t * C_A4)))) * expm2;

    EdgeOut o;
    o.ec = pref * (s + erfc - 1.0f);
    float fcl = pref * (damp * s * s + erfc + C_EWF * grij * expm2 - 1.0f);
    float fsc = fcl * frcp(r2);
    o.fx = dx * fsc; o.fy = dy * fsc; o.fz = dz * fsc;

    // ---- Dispersion (D3-CSO) ----
    float c6ij  = sqrtf(ar.y * ac.y);
    float r0ij  = 0.5f * (ar.z + ac.z);
    float r6    = r2 * r2 * r2 + C_45P6;
    float r6i   = frcp(r6);
    float e     = __expf(rij - 2.5f * r0ij);
    float onep  = frcp(1.0f + e);
    float cso   = 0.85f + 0.82f * onep;
    o.ed = -c6ij * r6i * cso + c6ij * C_DC6I;
    float r5  = r2 * r2 * rij;
    float fd  = -6.0f * c6ij * r5 * r6i * r6i * cso - c6ij * r6i * (0.82f * e * onep * onep);
    float gsc = fd * rinv;
    o.gx = dx * gsc; o.gy = dy * gsc; o.gz = dz * gsc;
    return o;
}

// Prologue: pack (f32 charge | f16 c6 | f16 r0) into one 8B record per atom.
__global__ __launch_bounds__(256) void pack_atoms8(
    const float* __restrict__ charge, const float* __restrict__ c6a,
    const float* __restrict__ r0a, vi2* __restrict__ tbl, int N)
{
    int i = blockIdx.x * blockDim.x + threadIdx.x;
    if (i < N) {
        vh2 h = __builtin_amdgcn_cvt_pkrtz(c6a[i], r0a[i]);
        union { vh2 h; int i; } u; u.h = h;
        vi2 v = { __float_as_int(charge[i]), u.i };
        tbl[i] = v;
    }
}

// ---------------------------------------------------------------------------
// One block = 1024 edges (4/thread), LDS transpose staging for all strided
// global accesses (R2 win). NEW this round: the 8 atom-table gathers bypass
// the CU L1 via agent-scope loads (sc0) -- probing the theory that the L1
// line-fill/MSHR tracking structure is the concurrency cap. sc0 also cuts
// L2->CU gather traffic from 64B/line-fill to 8B/request.
//
// Inline-asm load discipline:
//  - asm gathers are vmcnt-FIFO-ordered, so compiler-emitted vmcnt(N) waits
//    for its own loads remain conservative (never under-wait).
//  - our consume point: explicit s_waitcnt vmcnt(0) with "+v" ties on all 8
//    results + sched_barrier(0)  (rule #18: hipcc hoists reg-only ops past
//    inline-asm waitcnt otherwise).
// ---------------------------------------------------------------------------
__global__ __launch_bounds__(256, 4) void bamboo_lds8(
    const int* __restrict__ row, const int* __restrict__ col,
    const float* __restrict__ dij,
    const vi2* __restrict__ tbl,
    float* __restrict__ out, int E)
{
    __shared__ float s_a[256 * 13];   // dij in, then df
    __shared__ float s_b[256 * 13];   // cf

    const int t     = threadIdx.x;
    const int ebase = blockIdx.x << 10;
    const int gbase = ebase + t * 4;

    float* __restrict__ ec_o = out;
    float* __restrict__ cf_o = out + (size_t)E;
    float* __restrict__ ed_o = out + (size_t)4 * E;
    float* __restrict__ df_o = out + (size_t)5 * E;

    // ---- head of chain: indices (gathers depend on these) ----
    vi4 rr = __builtin_nontemporal_load((const vi4*)(row + gbase));
    vi4 cc = __builtin_nontemporal_load((const vi4*)(col + gbase));

    // ---- coalesced dij stream: 3 vf4/thread ----
    const vf4* dstream = (const vf4*)(dij + (size_t)ebase * 3);
    vf4 d0 = __builtin_nontemporal_load(dstream + (0 * 256 + t));
    vf4 d1 = __builtin_nontemporal_load(dstream + (1 * 256 + t));
    vf4 d2 = __builtin_nontemporal_load(dstream + (2 * 256 + t));
    __builtin_amdgcn_sched_barrier(0);

    // ---- all 8 gathers in flight back-to-back, L1-bypass (agent scope) ----
    vi2 g0r, g0c, g1r, g1c, g2r, g2c, g3r, g3c;
#define GLOAD(dst, idx) \
    asm volatile("global_load_dwordx2 %0, %1, off sc0" : "=v"(dst) : "v"(tbl + (idx)))
    GLOAD(g0r, rr.x); GLOAD(g0c, cc.x);
    GLOAD(g1r, rr.y); GLOAD(g1c, cc.y);
    GLOAD(g2r, rr.z); GLOAD(g2c, cc.z);
    GLOAD(g3r, rr.w); GLOAD(g3c, cc.w);
#undef GLOAD
    __builtin_amdgcn_sched_barrier(0);

    // ---- scatter coalesced dij vf4s into padded per-thread slots ----
    // vf4 index v holds flat floats 4v..4v+3 = slot q=v/3, dword 4r.
    {
        int v, q, r, b;
        v = 0 * 256 + t; q = v / 3; r = v - 3 * q; b = q * 13 + 4 * r;
        s_a[b + 0] = d0.x; s_a[b + 1] = d0.y; s_a[b + 2] = d0.z; s_a[b + 3] = d0.w;
        v = 1 * 256 + t; q = v / 3; r = v - 3 * q; b = q * 13 + 4 * r;
        s_a[b + 0] = d1.x; s_a[b + 1] = d1.y; s_a[b + 2] = d1.z; s_a[b + 3] = d1.w;
        v = 2 * 256 + t; q = v / 3; r = v - 3 * q; b = q * 13 + 4 * r;
        s_a[b + 0] = d2.x; s_a[b + 1] = d2.y; s_a[b + 2] = d2.z; s_a[b + 3] = d2.w;
    }
    __syncthreads();

    // ---- own dij: conflict-free stride-13 reads ----
    float d[12];
    #pragma unroll
    for (int m = 0; m < 12; ++m) d[m] = s_a[t * 13 + m];
    __syncthreads();                  // s_a free for reuse (df)

    // ---- consume point for the asm gathers ----
    asm volatile("s_waitcnt vmcnt(0)"
                 : "+v"(g0r), "+v"(g0c), "+v"(g1r), "+v"(g1c),
                   "+v"(g2r), "+v"(g2c), "+v"(g3r), "+v"(g3c));
    __builtin_amdgcn_sched_barrier(0);

    EdgeOut o0 = edge_compute(unpack8(g0r), unpack8(g0c), d[0], d[1],  d[2]);
    EdgeOut o1 = edge_compute(unpack8(g1r), unpack8(g1c), d[3], d[4],  d[5]);
    EdgeOut o2 = edge_compute(unpack8(g2r), unpack8(g2c), d[6], d[7],  d[8]);
    EdgeOut o3 = edge_compute(unpack8(g3r), unpack8(g3c), d[9], d[10], d[11]);

    // ---- ec/ed: already coalesced, store direct ----
    vf4 ec4 = { o0.ec, o1.ec, o2.ec, o3.ec };
    vf4 ed4 = { o0.ed, o1.ed, o2.ed, o3.ed };
    __builtin_nontemporal_store(ec4, (vf4*)(ec_o + gbase));
    __builtin_nontemporal_store(ed4, (vf4*)(ed_o + gbase));

    // ---- forces into LDS (stride-13, conflict-free) ----
    {
        float* cf = s_b + t * 13;
        float* df = s_a + t * 13;
        cf[0]  = o0.fx; cf[1]  = o0.fy; cf[2]  = o0.fz;
        cf[3]  = o1.fx; cf[4]  = o1.fy; cf[5]  = o1.fz;
        cf[6]  = o2.fx; cf[7]  = o2.fy; cf[8]  = o2.fz;
        cf[9]  = o3.fx; cf[10] = o3.fy; cf[11] = o3.fz;
        df[0]  = o0.gx; df[1]  = o0.gy; df[2]  = o0.gz;
        df[3]  = o1.gx; df[4]  = o1.gy; df[5]  = o1.gz;
        df[6]  = o2.gx; df[7]  = o2.gy; df[8]  = o2.gz;
        df[9]  = o3.gx; df[10] = o3.gy; df[11] = o3.gz;
    }
    __syncthreads();

    // ---- coalesced force store-out: 3 vf4/thread each ----
    vf4* cf_out = (vf4*)(cf_o + (size_t)ebase * 3);
    vf4* df_out = (vf4*)(df_o + (size_t)ebase * 3);
    #pragma unroll
    for (int j = 0; j < 3; ++j) {
        int v = j * 256 + t;
        int q = v / 3, r = v - 3 * q, b = q * 13 + 4 * r;
        vf4 wc = { s_b[b], s_b[b + 1], s_b[b + 2], s_b[b + 3] };
        __builtin_nontemporal_store(wc, cf_out + v);
        vf4 wd = { s_a[b], s_a[b + 1], s_a[b + 2], s_a[b + 3] };
        __builtin_nontemporal_store(wd, df_out + v);
    }

    // ---- tail edges (E % 1024), handled by block 0: no extra dispatch ----
    if (blockIdx.x == 0) {
        for (int j = ((int)gridDim.x << 10) + t; j < E; j += 256) {
            vi2 vr = tbl[row[j]];
            vi2 vc = tbl[col[j]];
            EdgeOut o = edge_compute(unpack8(vr), unpack8(vc),
                                     dij[3 * (size_t)j], dij[3 * (size_t)j + 1],
                                     dij[3 * (size_t)j + 2]);
            ec_o[j] = o.ec; ed_o[j] = o.ed;
            cf_o[3 * (size_t)j] = o.fx; cf_o[3 * (size_t)j + 1] = o.fy; cf_o[3 * (size_t)j + 2] = o.fz;
            df_o[3 * (size_t)j] = o.gx; df_o[3 * (size_t)j + 1] = o.gy; df_o[3 * (size_t)j + 2] = o.gz;
        }
    }
}

// Full scalar fallback (tiny workspace only).
__global__ __launch_bounds__(256) void bamboo_scalar(
    const int* __restrict__ row, const int* __restrict__ col,
    const float* __restrict__ dij,
    const float* __restrict__ charge, const float* __restrict__ c6a,
    const float* __restrict__ r0a,
    float* __restrict__ out, int E, int start)
{
    int j = start + blockIdx.x * blockDim.x + threadIdx.x;
    if (j >= E) return;
    float* ec_o = out;
    float* cf_o = out + (size_t)E;
    float* ed_o = out + (size_t)4 * E;
    float* df_o = out + (size_t)5 * E;
    int r = row[j], c = col[j];
    vf4 ar = { charge[r], c6a[r], r0a[r], 0.0f };
    vf4 ac = { charge[c], c6a[c], r0a[c], 0.0f };
    EdgeOut o = edge_compute(ar, ac,
                             dij[3 * (size_t)j], dij[3 * (size_t)j + 1], dij[3 * (size_t)j + 2]);
    ec_o[j] = o.ec; ed_o[j] = o.ed;
    cf_o[3 * (size_t)j] = o.fx; cf_o[3 * (size_t)j + 1] = o.fy; cf_o[3 * (size_t)j + 2] = o.fz;
    df_o[3 * (size_t)j] = o.gx; df_o[3 * (size_t)j + 1] = o.gy; df_o[3 * (size_t)j + 2] = o.gz;
}

extern "C" void kernel_launch(void* const* d_in, const int* in_sizes, int n_in,
                              void* d_out, int out_size, void* d_ws, size_t ws_size,
                              hipStream_t stream) {
    const int*   row    = (const int*)d_in[0];
    const int*   col    = (const int*)d_in[1];
    const float* dij    = (const float*)d_in[2];
    const float* charge = (const float*)d_in[3];
    const float* c6a    = (const float*)d_in[4];
    const float* r0a    = (const float*)d_in[5];
    float* out = (float*)d_out;
    int E = in_sizes[0];
    int N = in_sizes[3];

    size_t need = (size_t)N * sizeof(vi2);
    int ntiles = E >> 10;
    if (ws_size >= need && ((uintptr_t)d_ws % 8) == 0 && ntiles > 0) {
        vi2* tbl = (vi2*)d_ws;
        pack_atoms8<<<(N + 255) / 256, 256, 0, stream>>>(charge, c6a, r0a, tbl, N);
        bamboo_lds8<<<ntiles, 256, 0, stream>>>(row, col, dij, tbl, out, E);
    } else {
        bamboo_scalar<<<(E + 255) / 256, 256, 0, stream>>>(row, col, dij, charge, c6a, r0a, out, E, 0);
    }
}